// Round 8
// baseline (256.060 us; speedup 1.0000x reference)
//
#include <hip/hip_runtime.h>

#define N_ROWS 65536
#define N_COLS 256
#define NCLASS 10
#define XP 66176            // Xst col pitch: 65536 + 10*64 pad
#define SPL 16              // K-splits per (class,tile)
#define MSZ 65536           // 256*256 elements per matrix

typedef __attribute__((ext_vector_type(8))) short bf16x8;
typedef __attribute__((ext_vector_type(4))) float f32x4;

// meta layout (ints): [0..10] off_pad, [16..26] offsets (unpadded), [32..41] counts
// slab layout (bf16): s*11*MSZ + m*MSZ for s in {0:E, 1:G=E^2, 2:H=E^3, 3:K=E^4}

static __device__ __forceinline__ unsigned short f2bf(float f) {
    unsigned int u = __float_as_uint(f);
    unsigned int r = (u + 0x7FFFu + ((u >> 16) & 1u)) >> 16;   // RTN-even
    return (unsigned short)r;
}
static __device__ __forceinline__ float bf2f(unsigned short s) {
    return __uint_as_float(((unsigned int)s) << 16);
}
static __device__ __forceinline__ void unpack8(const unsigned short* p, float* f) {
    uint4 u = *(const uint4*)p;
    f[0] = __uint_as_float(u.x << 16); f[1] = __uint_as_float(u.x & 0xffff0000u);
    f[2] = __uint_as_float(u.y << 16); f[3] = __uint_as_float(u.y & 0xffff0000u);
    f[4] = __uint_as_float(u.z << 16); f[5] = __uint_as_float(u.z & 0xffff0000u);
    f[6] = __uint_as_float(u.w << 16); f[7] = __uint_as_float(u.w & 0xffff0000u);
}
static __device__ __forceinline__ float scal_of(int b, const int* meta) {
    if (b < NCLASS) return (float)N_COLS / (((float)meta[32 + b] + 1e-8f) * 0.01f);
    return (float)N_COLS / ((float)N_ROWS * 0.01f);
}

// ---------------- fused hist + scan + order (one block, 1024 threads) ----------------
// Thread t owns elements {t + 1024*j}. Register per-class counts -> LDS ->
// wave-per-class shuffle scan over thread index -> per-thread sequential placement.
// Within-class order is an arbitrary permutation: cov is permutation-invariant.
__global__ __launch_bounds__(1024) void sort_kernel(const int* __restrict__ Y,
                                                    int* __restrict__ meta,
                                                    int* __restrict__ order) {
    __shared__ int cnt_lds[NCLASS][1024];    // 40 KB
    __shared__ int base_lds[NCLASS][1024];   // 40 KB
    __shared__ int tot[16];
    __shared__ int soff[16];
    int t = threadIdx.x;

    int c0=0,c1=0,c2=0,c3=0,c4=0,c5=0,c6=0,c7=0,c8=0,c9=0;
    for (int j = 0; j < 64; ++j) {
        int y = Y[j * 1024 + t];
        c0+=(y==0); c1+=(y==1); c2+=(y==2); c3+=(y==3); c4+=(y==4);
        c5+=(y==5); c6+=(y==6); c7+=(y==7); c8+=(y==8); c9+=(y==9);
    }
    cnt_lds[0][t]=c0; cnt_lds[1][t]=c1; cnt_lds[2][t]=c2; cnt_lds[3][t]=c3;
    cnt_lds[4][t]=c4; cnt_lds[5][t]=c5; cnt_lds[6][t]=c6; cnt_lds[7][t]=c7;
    cnt_lds[8][t]=c8; cnt_lds[9][t]=c9;
    __syncthreads();

    int w = t >> 6, l = t & 63;
    if (w < NCLASS) {
        int run = 0;
        for (int ch = 0; ch < 16; ++ch) {
            int v = cnt_lds[w][ch * 64 + l];
            int x = v;
            #pragma unroll
            for (int d = 1; d < 64; d <<= 1) {
                int u = __shfl_up(x, d, 64);
                if (l >= d) x += u;
            }
            base_lds[w][ch * 64 + l] = run + x - v;   // exclusive prefix
            run += __shfl(x, 63, 64);
        }
        if (l == 0) tot[w] = run;
    }
    __syncthreads();
    if (t == 0) {
        int off = 0, offp = 0;
        for (int c = 0; c < NCLASS; ++c) {
            soff[c] = off;
            meta[16 + c] = off;
            meta[c] = offp;
            meta[32 + c] = tot[c];
            off += tot[c];
            offp += (tot[c] + 63) & ~63;
        }
        meta[16 + NCLASS] = off;
        meta[NCLASS] = offp;
    }
    __syncthreads();
    int p0_=soff[0]+base_lds[0][t], p1_=soff[1]+base_lds[1][t];
    int p2_=soff[2]+base_lds[2][t], p3_=soff[3]+base_lds[3][t];
    int p4_=soff[4]+base_lds[4][t], p5_=soff[5]+base_lds[5][t];
    int p6_=soff[6]+base_lds[6][t], p7_=soff[7]+base_lds[7][t];
    int p8_=soff[8]+base_lds[8][t], p9_=soff[9]+base_lds[9][t];
    for (int j = 0; j < 64; ++j) {
        int idx = j * 1024 + t;
        int y = Y[idx];
        if      (y == 0) order[p0_++] = idx;
        else if (y == 1) order[p1_++] = idx;
        else if (y == 2) order[p2_++] = idx;
        else if (y == 3) order[p3_++] = idx;
        else if (y == 4) order[p4_++] = idx;
        else if (y == 5) order[p5_++] = idx;
        else if (y == 6) order[p6_++] = idx;
        else if (y == 7) order[p7_++] = idx;
        else if (y == 8) order[p8_++] = idx;
        else if (y == 9) order[p9_++] = idx;
    }
}

// ---------------- gather + fp32->bf16 + transpose (rotation-swizzled LDS) ----------------
__global__ __launch_bounds__(256) void gather_kernel(const float* __restrict__ X,
                                                     const int* __restrict__ order,
                                                     const int* __restrict__ meta,
                                                     unsigned short* __restrict__ Xst) {
    __shared__ unsigned int sT32[256 * 32];   // 32 KB
    int p0 = blockIdx.x * 64;
    if (p0 >= meta[NCLASS]) return;
    int cls = 0;
    while (p0 >= meta[cls + 1]) ++cls;       // 64-tiles never straddle classes
    int lp0 = p0 - meta[cls];
    int cnt = meta[32 + cls];
    int obase = meta[16 + cls];

    int t = threadIdx.x;
    int w = t >> 6, l = t & 63;

    #pragma unroll
    for (int rp = 0; rp < 8; ++rp) {
        int p2 = w * 8 + rp;                  // 0..31 (pos pair index)
        int lpa = lp0 + p2 * 2;
        int lpb = lpa + 1;
        int ra = (lpa < cnt) ? order[obase + lpa] : -1;   // wave-uniform
        int rb = (lpb < cnt) ? order[obase + lpb] : -1;
        float4 va = make_float4(0.f, 0.f, 0.f, 0.f);
        float4 vb = make_float4(0.f, 0.f, 0.f, 0.f);
        if (ra >= 0) va = *(const float4*)(X + (size_t)ra * N_COLS + l * 4);
        if (rb >= 0) vb = *(const float4*)(X + (size_t)rb * N_COLS + l * 4);
        unsigned int d0 = (unsigned)f2bf(va.x) | ((unsigned)f2bf(vb.x) << 16);
        unsigned int d1 = (unsigned)f2bf(va.y) | ((unsigned)f2bf(vb.y) << 16);
        unsigned int d2 = (unsigned)f2bf(va.z) | ((unsigned)f2bf(vb.z) << 16);
        unsigned int d3 = (unsigned)f2bf(va.w) | ((unsigned)f2bf(vb.w) << 16);
        int c0 = l * 4;
        sT32[(c0 + 0) * 32 + ((p2 + l) & 31)] = d0;   // (c0+j)>>2 == l
        sT32[(c0 + 1) * 32 + ((p2 + l) & 31)] = d1;
        sT32[(c0 + 2) * 32 + ((p2 + l) & 31)] = d2;
        sT32[(c0 + 3) * 32 + ((p2 + l) & 31)] = d3;
    }
    __syncthreads();

    int cb = t >> 3, pc = t & 7;
    #pragma unroll
    for (int j = 0; j < 8; ++j) {
        int col = cb + j * 32;
        int rot = col >> 2;
        const unsigned int* base = &sT32[col * 32];
        uint4 o;
        o.x = base[(pc * 4 + 0 + rot) & 31];
        o.y = base[(pc * 4 + 1 + rot) & 31];
        o.z = base[(pc * 4 + 2 + rot) & 31];
        o.w = base[(pc * 4 + 3 + rot) & 31];
        *(uint4*)(Xst + (size_t)col * XP + p0 + pc * 8) = o;
    }
}

// ---------------- cov via bf16 MFMA syrk ----------------
__global__ __launch_bounds__(256) void cov_mfma(const unsigned short* __restrict__ Xst,
                                                const int* __restrict__ meta,
                                                float* __restrict__ cov) {
    __shared__ unsigned short sA[128][72];
    __shared__ unsigned short sB[128][72];
    int cls = blockIdx.y;
    int tile = blockIdx.x;
    int ti = (tile == 2) ? 1 : 0;
    int tj = (tile == 0) ? 0 : 1;
    int kb = meta[cls];
    int len = meta[cls + 1] - kb;
    int nch = len >> 6;
    int s = blockIdx.z;
    int ch0 = (nch * s) / SPL, ch1 = (nch * (s + 1)) / SPL;
    if (ch0 >= ch1) return;

    int t = threadIdx.x;
    int lane = t & 63, wave = t >> 6;
    int wro = (wave >> 1) * 64, wco = (wave & 1) * 64;

    f32x4 acc[4][4] = {};

    int sr = t >> 1;
    int sq = (t & 1) * 32;

    for (int ch = ch0; ch < ch1; ++ch) {
        int k0 = kb + ch * 64;
        const uint4* ga = (const uint4*)(Xst + (size_t)(ti * 128 + sr) * XP + k0 + sq);
        const uint4* gb = (const uint4*)(Xst + (size_t)(tj * 128 + sr) * XP + k0 + sq);
        uint4 a0 = ga[0], a1 = ga[1], a2 = ga[2], a3 = ga[3];
        uint4 b0 = gb[0], b1 = gb[1], b2 = gb[2], b3 = gb[3];
        __syncthreads();
        *(uint4*)&sA[sr][sq]      = a0;
        *(uint4*)&sA[sr][sq + 8]  = a1;
        *(uint4*)&sA[sr][sq + 16] = a2;
        *(uint4*)&sA[sr][sq + 24] = a3;
        *(uint4*)&sB[sr][sq]      = b0;
        *(uint4*)&sB[sr][sq + 8]  = b1;
        *(uint4*)&sB[sr][sq + 16] = b2;
        *(uint4*)&sB[sr][sq + 24] = b3;
        __syncthreads();
        #pragma unroll
        for (int ks = 0; ks < 64; ks += 32) {
            bf16x8 af[4], bfr[4];
            #pragma unroll
            for (int r = 0; r < 4; ++r)
                af[r] = *(const bf16x8*)&sA[wro + r * 16 + (lane & 15)][ks + (lane >> 4) * 8];
            #pragma unroll
            for (int c2 = 0; c2 < 4; ++c2)
                bfr[c2] = *(const bf16x8*)&sB[wco + c2 * 16 + (lane & 15)][ks + (lane >> 4) * 8];
            #pragma unroll
            for (int r = 0; r < 4; ++r) {
                #pragma unroll
                for (int c2 = 0; c2 < 4; ++c2)
                    acc[r][c2] = __builtin_amdgcn_mfma_f32_16x16x32_bf16(af[r], bfr[c2], acc[r][c2], 0, 0, 0);
            }
        }
    }

    float* cb = cov + (size_t)cls * MSZ;
    int prow = ti * 128 + wro + ((lane >> 4) << 2);
    int pcol = tj * 128 + wco + (lane & 15);
    #pragma unroll
    for (int r = 0; r < 4; ++r) {
        #pragma unroll
        for (int c2 = 0; c2 < 4; ++c2) {
            #pragma unroll
            for (int v = 0; v < 4; ++v)
                atomicAdd(&cb[(size_t)(prow + r * 16 + v) * N_COLS + pcol + c2 * 16], acc[r][c2][v]);
        }
    }
}

// ---------------- prep: inline cvals + E_b = M_b/c_b - I (bf16); grid (11, 32) ----------------
__global__ __launch_bounds__(256) void prep_kernel(const float* __restrict__ cov,
                                                   const int* __restrict__ meta,
                                                   float* __restrict__ cvals,
                                                   unsigned short* __restrict__ slab) {
    int b = blockIdx.x;   // matrix 0..10
    int t = threadIdx.x;
    float scal = scal_of(b, meta);

    // every block reduces the diagonal (1 KB, L2-hot) -> no separate cvals launch
    float dsum;
    if (b < NCLASS) dsum = cov[(size_t)b * MSZ + t * 257];
    else {
        dsum = 0.f;
        #pragma unroll
        for (int cl = 0; cl < NCLASS; ++cl) dsum += cov[(size_t)cl * MSZ + t * 257];
    }
    __shared__ float red[256];
    red[t] = dsum;
    __syncthreads();
    for (int s = 128; s > 0; s >>= 1) {
        if (t < s) red[t] += red[t + s];
        __syncthreads();
    }
    float c = 1.f + scal * red[0] / 256.f;
    if (blockIdx.y == 0 && t == 0) cvals[b] = c;
    float es = scal / c;
    float dadd = 1.f / c - 1.f;

    int i  = blockIdx.y * 8 + (t >> 5);   // row
    int cg = (t & 31) * 8;                // col group (8 elems)
    bool mb = (i >> 7) > (cg >> 7);       // cov stores upper 128-blocks; mirror (1,0)
    float v[8];
    if (!mb) {
        size_t off = (size_t)i * N_COLS + cg;
        if (b < NCLASS) {
            float4 a = *(const float4*)(cov + (size_t)b * MSZ + off);
            float4 bq = *(const float4*)(cov + (size_t)b * MSZ + off + 4);
            v[0] = a.x; v[1] = a.y; v[2] = a.z; v[3] = a.w;
            v[4] = bq.x; v[5] = bq.y; v[6] = bq.z; v[7] = bq.w;
        } else {
            #pragma unroll
            for (int jj = 0; jj < 8; ++jj) v[jj] = 0.f;
            #pragma unroll
            for (int cl = 0; cl < NCLASS; ++cl) {
                float4 a = *(const float4*)(cov + (size_t)cl * MSZ + off);
                float4 bq = *(const float4*)(cov + (size_t)cl * MSZ + off + 4);
                v[0] += a.x; v[1] += a.y; v[2] += a.z; v[3] += a.w;
                v[4] += bq.x; v[5] += bq.y; v[6] += bq.z; v[7] += bq.w;
            }
        }
    } else {
        #pragma unroll
        for (int jj = 0; jj < 8; ++jj) {
            size_t off = (size_t)(cg + jj) * N_COLS + i;
            float s;
            if (b < NCLASS) s = cov[(size_t)b * MSZ + off];
            else {
                s = 0.f;
                #pragma unroll
                for (int cl = 0; cl < NCLASS; ++cl) s += cov[(size_t)cl * MSZ + off];
            }
            v[jj] = s;
        }
    }
    unsigned short o[8];
    #pragma unroll
    for (int jj = 0; jj < 8; ++jj)
        o[jj] = f2bf(es * v[jj] + ((cg + jj) == i ? dadd : 0.f));
    uint4 pk;
    pk.x = (unsigned)o[0] | ((unsigned)o[1] << 16);
    pk.y = (unsigned)o[2] | ((unsigned)o[3] << 16);
    pk.z = (unsigned)o[4] | ((unsigned)o[5] << 16);
    pk.w = (unsigned)o[6] | ((unsigned)o[7] << 16);
    *(uint4*)&slab[(size_t)b * MSZ + (size_t)i * N_COLS + cg] = pk;
}

// ---------------- mm_stage: D = A*B^T (=A*B, symmetric) bf16 256x256 (MFMA) ----------------
__global__ __launch_bounds__(256) void mm_stage(unsigned short* __restrict__ slab,
                                                int ai0, int bi0, int di0,
                                                int ai1, int bi1, int di1) {
    int z = blockIdx.z;
    int ai = z ? ai1 : ai0, bi = z ? bi1 : bi0, di = z ? di1 : di0;
    int m = blockIdx.y;
    int tile = blockIdx.x;
    int ti = tile >> 1, tj = tile & 1;
    const unsigned short* A = slab + ((size_t)ai * 11 + m) * MSZ;
    const unsigned short* B = slab + ((size_t)bi * 11 + m) * MSZ;
    unsigned short* D = slab + ((size_t)di * 11 + m) * MSZ;

    __shared__ unsigned short sA[128][72];
    __shared__ unsigned short sB[128][72];
    int t = threadIdx.x;
    int lane = t & 63, wave = t >> 6;
    int wro = (wave >> 1) * 64, wco = (wave & 1) * 64;

    f32x4 acc[4][4] = {};
    int sr = t >> 1;
    int sq = (t & 1) * 32;

    for (int ch = 0; ch < 4; ++ch) {
        int k0 = ch * 64;
        const uint4* ga = (const uint4*)(A + (size_t)(ti * 128 + sr) * N_COLS + k0 + sq);
        const uint4* gb = (const uint4*)(B + (size_t)(tj * 128 + sr) * N_COLS + k0 + sq);
        uint4 a0 = ga[0], a1 = ga[1], a2 = ga[2], a3 = ga[3];
        uint4 b0 = gb[0], b1 = gb[1], b2 = gb[2], b3 = gb[3];
        __syncthreads();
        *(uint4*)&sA[sr][sq]      = a0;
        *(uint4*)&sA[sr][sq + 8]  = a1;
        *(uint4*)&sA[sr][sq + 16] = a2;
        *(uint4*)&sA[sr][sq + 24] = a3;
        *(uint4*)&sB[sr][sq]      = b0;
        *(uint4*)&sB[sr][sq + 8]  = b1;
        *(uint4*)&sB[sr][sq + 16] = b2;
        *(uint4*)&sB[sr][sq + 24] = b3;
        __syncthreads();
        #pragma unroll
        for (int ks = 0; ks < 64; ks += 32) {
            bf16x8 af[4], bfr[4];
            #pragma unroll
            for (int r = 0; r < 4; ++r)
                af[r] = *(const bf16x8*)&sA[wro + r * 16 + (lane & 15)][ks + (lane >> 4) * 8];
            #pragma unroll
            for (int c2 = 0; c2 < 4; ++c2)
                bfr[c2] = *(const bf16x8*)&sB[wco + c2 * 16 + (lane & 15)][ks + (lane >> 4) * 8];
            #pragma unroll
            for (int r = 0; r < 4; ++r) {
                #pragma unroll
                for (int c2 = 0; c2 < 4; ++c2)
                    acc[r][c2] = __builtin_amdgcn_mfma_f32_16x16x32_bf16(af[r], bfr[c2], acc[r][c2], 0, 0, 0);
            }
        }
    }

    int prow = ti * 128 + wro + ((lane >> 4) << 2);
    int pcol = tj * 128 + wco + (lane & 15);
    #pragma unroll
    for (int r = 0; r < 4; ++r) {
        #pragma unroll
        for (int c2 = 0; c2 < 4; ++c2) {
            #pragma unroll
            for (int v = 0; v < 4; ++v)
                D[(size_t)(prow + r * 16 + v) * N_COLS + pcol + c2 * 16] = f2bf(acc[r][c2][v]);
        }
    }
}

// ---------------- trace: pairings of E,G,H,K -> tr(E^k), k=1..8; grid (11, 8) ----------------
// traces[m*16 + v]: v=0:tr2 1:tr3 2:tr4 3:tr5 4:tr6 5:tr7 6:tr8 7:tr1
__global__ __launch_bounds__(256) void trace_kernel(const unsigned short* __restrict__ slab,
                                                    float* __restrict__ traces) {
    int m = blockIdx.x, t = threadIdx.x;
    int r  = blockIdx.y * 32 + (t >> 3);   // row
    int cs = (t & 7) * 32;                 // col segment (32 elems)
    const unsigned short* E = slab + (size_t)m * MSZ;
    const unsigned short* G = E + (size_t)11 * MSZ;
    const unsigned short* H = E + (size_t)22 * MSZ;
    const unsigned short* K = E + (size_t)33 * MSZ;

    float a0 = 0, a1 = 0, a2 = 0, a3 = 0, a4 = 0, a5 = 0, a6 = 0;
    float t1 = (r >= cs && r < cs + 32) ? bf2f(E[(size_t)r * 257]) : 0.f;
    size_t rb = (size_t)r * N_COLS + cs;
    #pragma unroll
    for (int cg = 0; cg < 32; cg += 8) {
        float e[8], g[8], h[8], k[8];
        unpack8(E + rb + cg, e);
        unpack8(G + rb + cg, g);
        unpack8(H + rb + cg, h);
        unpack8(K + rb + cg, k);
        #pragma unroll
        for (int j = 0; j < 8; ++j) {
            a0 = fmaf(e[j], e[j], a0);   // tr2
            a1 = fmaf(e[j], g[j], a1);   // tr3
            a2 = fmaf(g[j], g[j], a2);   // tr4
            a3 = fmaf(g[j], h[j], a3);   // tr5
            a4 = fmaf(h[j], h[j], a4);   // tr6
            a5 = fmaf(h[j], k[j], a5);   // tr7
            a6 = fmaf(k[j], k[j], a6);   // tr8
        }
    }
    float vals[8] = {a0, a1, a2, a3, a4, a5, a6, t1};
    #pragma unroll
    for (int v = 0; v < 8; ++v) {
        float x = vals[v];
        #pragma unroll
        for (int d = 32; d > 0; d >>= 1) x += __shfl_down(x, d, 64);
        if ((t & 63) == 0) atomicAdd(&traces[m * 16 + v], x);
    }
}

// ---------------- finalize (degree-8 series) ----------------
__global__ void finalize_kernel(const float* __restrict__ traces,
                                const float* __restrict__ cvals,
                                const int* __restrict__ meta,
                                float* __restrict__ out) {
    if (threadIdx.x == 0 && blockIdx.x == 0) {
        float logdet[11];
        for (int m = 0; m < 11; ++m) {
            const float* tr = traces + m * 16;
            logdet[m] = 256.f * __logf(cvals[m])
                      + tr[7]
                      - tr[0] / 2.f + tr[1] / 3.f - tr[2] / 4.f + tr[3] / 5.f
                      - tr[4] / 6.f + tr[5] / 7.f - tr[6] / 8.f;
        }
        float discrimn = 0.5f * logdet[NCLASS];       // GAM1 == 1 => empi == theo
        float compress = 0.f;
        for (int k = 0; k < NCLASS; ++k) {
            float trp = (float)meta[32 + k] + 1e-8f;
            compress += logdet[k] * trp;
        }
        compress = compress / (float)N_ROWS * 0.5f;
        out[0] = -discrimn + compress;                // GAM2 == 1
        out[1] = discrimn;
        out[2] = compress;
        out[3] = discrimn;
        out[4] = compress;
    }
}

extern "C" void kernel_launch(void* const* d_in, const int* in_sizes, int n_in,
                              void* d_out, int out_size, void* d_ws, size_t ws_size,
                              hipStream_t stream) {
    const float* X = (const float*)d_in[0];
    const int*   Y = (const int*)d_in[1];
    float* out = (float*)d_out;

    char* ws = (char*)d_ws;
    const size_t o_cov   = 0;                        // 10*256*256*4 = 2,621,440
    const size_t o_small = 2621440;                  // cvals (16 f) + traces (176 f); adjacent to cov -> one memset
    const size_t o_meta  = o_small + 1024;           // 64 ints
    const size_t o_order = o_meta + 256;             // 65536 ints
    const size_t o_xst   = o_order + 262144;         // 256*XP*2 = 33,882,112

    float*          cov      = (float*)(ws + o_cov);
    float*          cvals    = (float*)(ws + o_small);
    float*          traces   = (float*)(ws + o_small + 64);
    int*            meta     = (int*)(ws + o_meta);
    int*            order    = (int*)(ws + o_order);
    unsigned short* Xst      = (unsigned short*)(ws + o_xst);
    unsigned short* slab     = Xst;                  // E/G/H/K overlay Xst after cov

    hipMemsetAsync(ws, 0, o_small + 1024, stream);   // cov + cvals + traces in one fill
    hipLaunchKernelGGL(sort_kernel, dim3(1), dim3(1024), 0, stream, Y, meta, order);
    hipLaunchKernelGGL(gather_kernel, dim3(XP / 64), dim3(256), 0, stream, X, order, meta, Xst);
    hipLaunchKernelGGL(cov_mfma, dim3(3, NCLASS, SPL), dim3(256), 0, stream, Xst, meta, cov);
    hipLaunchKernelGGL(prep_kernel, dim3(11, 32), dim3(256), 0, stream, cov, meta, cvals, slab);
    // S1: G = E*E
    hipLaunchKernelGGL(mm_stage, dim3(4, 11, 1), dim3(256), 0, stream, slab, 0, 0, 1, 0, 0, 1);
    // S2: H = E*G ; K = G*G
    hipLaunchKernelGGL(mm_stage, dim3(4, 11, 2), dim3(256), 0, stream, slab, 0, 1, 2, 1, 1, 3);
    hipLaunchKernelGGL(trace_kernel, dim3(11, 8), dim3(256), 0, stream, slab, traces);
    hipLaunchKernelGGL(finalize_kernel, dim3(1), dim3(64), 0, stream, traces, cvals, meta, out);
}

// Round 9
// 191.813 us; speedup vs baseline: 1.3349x; 1.3349x over previous
//
#include <hip/hip_runtime.h>

#define N_ROWS 65536
#define N_COLS 256
#define NCLASS 10
#define XP 66176            // Xst col pitch: 65536 + 10*64 pad
#define SPL 16              // K-splits per (class,tile)
#define MSZ 65536           // 256*256 elements per matrix

typedef __attribute__((ext_vector_type(8))) short bf16x8;
typedef __attribute__((ext_vector_type(4))) float f32x4;

// meta layout (ints): [0..10] off_pad, [16..26] offsets (unpadded), [32..41] counts
// slab layout (bf16): s*11*MSZ + m*MSZ for s in {0:E, 1:G=E^2, 2:H=E^3, 3:K=E^4}

static __device__ __forceinline__ unsigned short f2bf(float f) {
    unsigned int u = __float_as_uint(f);
    unsigned int r = (u + 0x7FFFu + ((u >> 16) & 1u)) >> 16;   // RTN-even
    return (unsigned short)r;
}
static __device__ __forceinline__ float bf2f(unsigned short s) {
    return __uint_as_float(((unsigned int)s) << 16);
}
static __device__ __forceinline__ void unpack8(const unsigned short* p, float* f) {
    uint4 u = *(const uint4*)p;
    f[0] = __uint_as_float(u.x << 16); f[1] = __uint_as_float(u.x & 0xffff0000u);
    f[2] = __uint_as_float(u.y << 16); f[3] = __uint_as_float(u.y & 0xffff0000u);
    f[4] = __uint_as_float(u.z << 16); f[5] = __uint_as_float(u.z & 0xffff0000u);
    f[6] = __uint_as_float(u.w << 16); f[7] = __uint_as_float(u.w & 0xffff0000u);
}
static __device__ __forceinline__ float scal_of(int b, const int* meta) {
    if (b < NCLASS) return (float)N_COLS / (((float)meta[32 + b] + 1e-8f) * 0.01f);
    return (float)N_COLS / ((float)N_ROWS * 0.01f);
}

// ---------------- Phase A: per-block class histogram (256 blocks) ----------------
__global__ __launch_bounds__(256) void blkhist_kernel(const int* __restrict__ Y,
                                                      int* __restrict__ blk_cnt) {
    __shared__ int h[NCLASS];
    int b = blockIdx.x, t = threadIdx.x;
    if (t < NCLASS) h[t] = 0;
    __syncthreads();
    atomicAdd(&h[Y[b * 256 + t]], 1);
    __syncthreads();
    if (t < NCLASS) blk_cnt[b * NCLASS + t] = h[t];
}

// ---------------- Phase B: scan (wave-per-class shuffle scans, 1 block) ----------------
__global__ __launch_bounds__(1024) void scan_kernel(const int* __restrict__ blk_cnt,
                                                    int* __restrict__ meta,
                                                    int* __restrict__ blk_base) {
    int t = threadIdx.x;
    int w = t >> 6, l = t & 63;
    __shared__ int tots[16];
    __shared__ int soff_s[16];
    int s0 = 0, s1 = 0, s2 = 0, s3 = 0;
    if (w < NCLASS) {
        s0 = blk_cnt[(l      ) * NCLASS + w];
        s1 = blk_cnt[(l +  64) * NCLASS + w];
        s2 = blk_cnt[(l + 128) * NCLASS + w];
        s3 = blk_cnt[(l + 192) * NCLASS + w];
    }
    int x0 = s0, x1 = s1, x2 = s2, x3 = s3;
    for (int d = 1; d < 64; d <<= 1) {
        int y0 = __shfl_up(x0, d, 64), y1 = __shfl_up(x1, d, 64);
        int y2 = __shfl_up(x2, d, 64), y3 = __shfl_up(x3, d, 64);
        if (l >= d) { x0 += y0; x1 += y1; x2 += y2; x3 += y3; }
    }
    int T0 = __shfl(x0, 63, 64), T1 = __shfl(x1, 63, 64);
    int T2 = __shfl(x2, 63, 64), T3 = __shfl(x3, 63, 64);
    if (w < NCLASS && l == 63) tots[w] = T0 + T1 + T2 + T3;
    __syncthreads();
    if (t == 0) {
        int off = 0, offp = 0;
        for (int c = 0; c < NCLASS; ++c) {
            soff_s[c] = off;
            meta[16 + c] = off;
            meta[c] = offp;
            meta[32 + c] = tots[c];
            off += tots[c];
            offp += (tots[c] + 63) & ~63;
        }
        meta[16 + NCLASS] = off;
        meta[NCLASS] = offp;
    }
    __syncthreads();
    if (w < NCLASS) {
        int base = soff_s[w];
        blk_base[(l      ) * NCLASS + w] = base + x0 - s0;
        blk_base[(l +  64) * NCLASS + w] = base + T0 + x1 - s1;
        blk_base[(l + 128) * NCLASS + w] = base + T0 + T1 + x2 - s2;
        blk_base[(l + 192) * NCLASS + w] = base + T0 + T1 + T2 + x3 - s3;
    }
}

// ---------------- Phase C: build sorted order (256 blocks) ----------------
__global__ __launch_bounds__(256) void order_kernel(const int* __restrict__ Y,
                                                    const int* __restrict__ blk_base,
                                                    int* __restrict__ order) {
    __shared__ int lcur[NCLASS];
    int b = blockIdx.x, t = threadIdx.x;
    if (t < NCLASS) lcur[t] = 0;
    __syncthreads();
    int i = b * 256 + t;
    int y = Y[i];
    int pos = blk_base[b * NCLASS + y] + atomicAdd(&lcur[y], 1);
    order[pos] = i;
}

// ---------------- gather + fp32->bf16 + transpose (rotation-swizzled LDS) ----------------
__global__ __launch_bounds__(256) void gather_kernel(const float* __restrict__ X,
                                                     const int* __restrict__ order,
                                                     const int* __restrict__ meta,
                                                     unsigned short* __restrict__ Xst) {
    __shared__ unsigned int sT32[256 * 32];   // 32 KB
    int p0 = blockIdx.x * 64;
    if (p0 >= meta[NCLASS]) return;
    int cls = 0;
    while (p0 >= meta[cls + 1]) ++cls;       // 64-tiles never straddle classes
    int lp0 = p0 - meta[cls];
    int cnt = meta[32 + cls];
    int obase = meta[16 + cls];

    int t = threadIdx.x;
    int w = t >> 6, l = t & 63;

    #pragma unroll
    for (int rp = 0; rp < 8; ++rp) {
        int p2 = w * 8 + rp;                  // 0..31 (pos pair index)
        int lpa = lp0 + p2 * 2;
        int lpb = lpa + 1;
        int ra = (lpa < cnt) ? order[obase + lpa] : -1;   // wave-uniform
        int rb = (lpb < cnt) ? order[obase + lpb] : -1;
        float4 va = make_float4(0.f, 0.f, 0.f, 0.f);
        float4 vb = make_float4(0.f, 0.f, 0.f, 0.f);
        if (ra >= 0) va = *(const float4*)(X + (size_t)ra * N_COLS + l * 4);
        if (rb >= 0) vb = *(const float4*)(X + (size_t)rb * N_COLS + l * 4);
        unsigned int d0 = (unsigned)f2bf(va.x) | ((unsigned)f2bf(vb.x) << 16);
        unsigned int d1 = (unsigned)f2bf(va.y) | ((unsigned)f2bf(vb.y) << 16);
        unsigned int d2 = (unsigned)f2bf(va.z) | ((unsigned)f2bf(vb.z) << 16);
        unsigned int d3 = (unsigned)f2bf(va.w) | ((unsigned)f2bf(vb.w) << 16);
        int c0 = l * 4;
        sT32[(c0 + 0) * 32 + ((p2 + l) & 31)] = d0;   // (c0+j)>>2 == l
        sT32[(c0 + 1) * 32 + ((p2 + l) & 31)] = d1;
        sT32[(c0 + 2) * 32 + ((p2 + l) & 31)] = d2;
        sT32[(c0 + 3) * 32 + ((p2 + l) & 31)] = d3;
    }
    __syncthreads();

    int cb = t >> 3, pc = t & 7;
    #pragma unroll
    for (int j = 0; j < 8; ++j) {
        int col = cb + j * 32;
        int rot = col >> 2;
        const unsigned int* base = &sT32[col * 32];
        uint4 o;
        o.x = base[(pc * 4 + 0 + rot) & 31];
        o.y = base[(pc * 4 + 1 + rot) & 31];
        o.z = base[(pc * 4 + 2 + rot) & 31];
        o.w = base[(pc * 4 + 3 + rot) & 31];
        *(uint4*)(Xst + (size_t)col * XP + p0 + pc * 8) = o;
    }
}

// ---------------- cov via bf16 MFMA syrk ----------------
__global__ __launch_bounds__(256) void cov_mfma(const unsigned short* __restrict__ Xst,
                                                const int* __restrict__ meta,
                                                float* __restrict__ cov) {
    __shared__ unsigned short sA[128][72];
    __shared__ unsigned short sB[128][72];
    int cls = blockIdx.y;
    int tile = blockIdx.x;
    int ti = (tile == 2) ? 1 : 0;
    int tj = (tile == 0) ? 0 : 1;
    int kb = meta[cls];
    int len = meta[cls + 1] - kb;
    int nch = len >> 6;
    int s = blockIdx.z;
    int ch0 = (nch * s) / SPL, ch1 = (nch * (s + 1)) / SPL;
    if (ch0 >= ch1) return;

    int t = threadIdx.x;
    int lane = t & 63, wave = t >> 6;
    int wro = (wave >> 1) * 64, wco = (wave & 1) * 64;

    f32x4 acc[4][4] = {};

    int sr = t >> 1;
    int sq = (t & 1) * 32;

    for (int ch = ch0; ch < ch1; ++ch) {
        int k0 = kb + ch * 64;
        const uint4* ga = (const uint4*)(Xst + (size_t)(ti * 128 + sr) * XP + k0 + sq);
        const uint4* gb = (const uint4*)(Xst + (size_t)(tj * 128 + sr) * XP + k0 + sq);
        uint4 a0 = ga[0], a1 = ga[1], a2 = ga[2], a3 = ga[3];
        uint4 b0 = gb[0], b1 = gb[1], b2 = gb[2], b3 = gb[3];
        __syncthreads();
        *(uint4*)&sA[sr][sq]      = a0;
        *(uint4*)&sA[sr][sq + 8]  = a1;
        *(uint4*)&sA[sr][sq + 16] = a2;
        *(uint4*)&sA[sr][sq + 24] = a3;
        *(uint4*)&sB[sr][sq]      = b0;
        *(uint4*)&sB[sr][sq + 8]  = b1;
        *(uint4*)&sB[sr][sq + 16] = b2;
        *(uint4*)&sB[sr][sq + 24] = b3;
        __syncthreads();
        #pragma unroll
        for (int ks = 0; ks < 64; ks += 32) {
            bf16x8 af[4], bfr[4];
            #pragma unroll
            for (int r = 0; r < 4; ++r)
                af[r] = *(const bf16x8*)&sA[wro + r * 16 + (lane & 15)][ks + (lane >> 4) * 8];
            #pragma unroll
            for (int c2 = 0; c2 < 4; ++c2)
                bfr[c2] = *(const bf16x8*)&sB[wco + c2 * 16 + (lane & 15)][ks + (lane >> 4) * 8];
            #pragma unroll
            for (int r = 0; r < 4; ++r) {
                #pragma unroll
                for (int c2 = 0; c2 < 4; ++c2)
                    acc[r][c2] = __builtin_amdgcn_mfma_f32_16x16x32_bf16(af[r], bfr[c2], acc[r][c2], 0, 0, 0);
            }
        }
    }

    float* cb = cov + (size_t)cls * MSZ;
    int prow = ti * 128 + wro + ((lane >> 4) << 2);
    int pcol = tj * 128 + wco + (lane & 15);
    #pragma unroll
    for (int r = 0; r < 4; ++r) {
        #pragma unroll
        for (int c2 = 0; c2 < 4; ++c2) {
            #pragma unroll
            for (int v = 0; v < 4; ++v)
                atomicAdd(&cb[(size_t)(prow + r * 16 + v) * N_COLS + pcol + c2 * 16], acc[r][c2][v]);
        }
    }
}

// ---------------- prep: inline cvals + E_b = M_b/c_b - I (bf16); grid (11, 32) ----------------
__global__ __launch_bounds__(256) void prep_kernel(const float* __restrict__ cov,
                                                   const int* __restrict__ meta,
                                                   float* __restrict__ cvals,
                                                   unsigned short* __restrict__ slab) {
    int b = blockIdx.x;   // matrix 0..10
    int t = threadIdx.x;
    float scal = scal_of(b, meta);

    // every block reduces the diagonal (1 KB, L2-hot) -> no separate cvals launch
    float dsum;
    if (b < NCLASS) dsum = cov[(size_t)b * MSZ + t * 257];
    else {
        dsum = 0.f;
        #pragma unroll
        for (int cl = 0; cl < NCLASS; ++cl) dsum += cov[(size_t)cl * MSZ + t * 257];
    }
    __shared__ float red[256];
    red[t] = dsum;
    __syncthreads();
    for (int s = 128; s > 0; s >>= 1) {
        if (t < s) red[t] += red[t + s];
        __syncthreads();
    }
    float c = 1.f + scal * red[0] / 256.f;
    if (blockIdx.y == 0 && t == 0) cvals[b] = c;
    float es = scal / c;
    float dadd = 1.f / c - 1.f;

    int i  = blockIdx.y * 8 + (t >> 5);   // row
    int cg = (t & 31) * 8;                // col group (8 elems)
    bool mb = (i >> 7) > (cg >> 7);       // cov stores upper 128-blocks; mirror (1,0)
    float v[8];
    if (!mb) {
        size_t off = (size_t)i * N_COLS + cg;
        if (b < NCLASS) {
            float4 a = *(const float4*)(cov + (size_t)b * MSZ + off);
            float4 bq = *(const float4*)(cov + (size_t)b * MSZ + off + 4);
            v[0] = a.x; v[1] = a.y; v[2] = a.z; v[3] = a.w;
            v[4] = bq.x; v[5] = bq.y; v[6] = bq.z; v[7] = bq.w;
        } else {
            #pragma unroll
            for (int jj = 0; jj < 8; ++jj) v[jj] = 0.f;
            #pragma unroll
            for (int cl = 0; cl < NCLASS; ++cl) {
                float4 a = *(const float4*)(cov + (size_t)cl * MSZ + off);
                float4 bq = *(const float4*)(cov + (size_t)cl * MSZ + off + 4);
                v[0] += a.x; v[1] += a.y; v[2] += a.z; v[3] += a.w;
                v[4] += bq.x; v[5] += bq.y; v[6] += bq.z; v[7] += bq.w;
            }
        }
    } else {
        #pragma unroll
        for (int jj = 0; jj < 8; ++jj) {
            size_t off = (size_t)(cg + jj) * N_COLS + i;
            float s;
            if (b < NCLASS) s = cov[(size_t)b * MSZ + off];
            else {
                s = 0.f;
                #pragma unroll
                for (int cl = 0; cl < NCLASS; ++cl) s += cov[(size_t)cl * MSZ + off];
            }
            v[jj] = s;
        }
    }
    unsigned short o[8];
    #pragma unroll
    for (int jj = 0; jj < 8; ++jj)
        o[jj] = f2bf(es * v[jj] + ((cg + jj) == i ? dadd : 0.f));
    uint4 pk;
    pk.x = (unsigned)o[0] | ((unsigned)o[1] << 16);
    pk.y = (unsigned)o[2] | ((unsigned)o[3] << 16);
    pk.z = (unsigned)o[4] | ((unsigned)o[5] << 16);
    pk.w = (unsigned)o[6] | ((unsigned)o[7] << 16);
    *(uint4*)&slab[(size_t)b * MSZ + (size_t)i * N_COLS + cg] = pk;
}

// ---------------- mm_stage: D = A*B for symmetric bf16 256x256 (MFMA) ----------------
__global__ __launch_bounds__(256) void mm_stage(unsigned short* __restrict__ slab,
                                                int ai0, int bi0, int di0,
                                                int ai1, int bi1, int di1) {
    int z = blockIdx.z;
    int ai = z ? ai1 : ai0, bi = z ? bi1 : bi0, di = z ? di1 : di0;
    int m = blockIdx.y;
    int tile = blockIdx.x;
    int ti = tile >> 1, tj = tile & 1;
    const unsigned short* A = slab + ((size_t)ai * 11 + m) * MSZ;
    const unsigned short* B = slab + ((size_t)bi * 11 + m) * MSZ;
    unsigned short* D = slab + ((size_t)di * 11 + m) * MSZ;

    __shared__ unsigned short sA[128][72];
    __shared__ unsigned short sB[128][72];
    int t = threadIdx.x;
    int lane = t & 63, wave = t >> 6;
    int wro = (wave >> 1) * 64, wco = (wave & 1) * 64;

    f32x4 acc[4][4] = {};
    int sr = t >> 1;
    int sq = (t & 1) * 32;

    for (int ch = 0; ch < 4; ++ch) {
        int k0 = ch * 64;
        const uint4* ga = (const uint4*)(A + (size_t)(ti * 128 + sr) * N_COLS + k0 + sq);
        const uint4* gb = (const uint4*)(B + (size_t)(tj * 128 + sr) * N_COLS + k0 + sq);
        uint4 a0 = ga[0], a1 = ga[1], a2 = ga[2], a3 = ga[3];
        uint4 b0 = gb[0], b1 = gb[1], b2 = gb[2], b3 = gb[3];
        __syncthreads();
        *(uint4*)&sA[sr][sq]      = a0;
        *(uint4*)&sA[sr][sq + 8]  = a1;
        *(uint4*)&sA[sr][sq + 16] = a2;
        *(uint4*)&sA[sr][sq + 24] = a3;
        *(uint4*)&sB[sr][sq]      = b0;
        *(uint4*)&sB[sr][sq + 8]  = b1;
        *(uint4*)&sB[sr][sq + 16] = b2;
        *(uint4*)&sB[sr][sq + 24] = b3;
        __syncthreads();
        #pragma unroll
        for (int ks = 0; ks < 64; ks += 32) {
            bf16x8 af[4], bfr[4];
            #pragma unroll
            for (int r = 0; r < 4; ++r)
                af[r] = *(const bf16x8*)&sA[wro + r * 16 + (lane & 15)][ks + (lane >> 4) * 8];
            #pragma unroll
            for (int c2 = 0; c2 < 4; ++c2)
                bfr[c2] = *(const bf16x8*)&sB[wco + c2 * 16 + (lane & 15)][ks + (lane >> 4) * 8];
            #pragma unroll
            for (int r = 0; r < 4; ++r) {
                #pragma unroll
                for (int c2 = 0; c2 < 4; ++c2)
                    acc[r][c2] = __builtin_amdgcn_mfma_f32_16x16x32_bf16(af[r], bfr[c2], acc[r][c2], 0, 0, 0);
            }
        }
    }

    int prow = ti * 128 + wro + ((lane >> 4) << 2);
    int pcol = tj * 128 + wco + (lane & 15);
    #pragma unroll
    for (int r = 0; r < 4; ++r) {
        #pragma unroll
        for (int c2 = 0; c2 < 4; ++c2) {
            #pragma unroll
            for (int v = 0; v < 4; ++v)
                D[(size_t)(prow + r * 16 + v) * N_COLS + pcol + c2 * 16] = f2bf(acc[r][c2][v]);
        }
    }
}

// ---------------- trace: pairings of E,G,H,K -> tr(E^k), k=1..8; grid (11, 8) ----------------
// traces[m*16 + v]: v=0:tr2 1:tr3 2:tr4 3:tr5 4:tr6 5:tr7 6:tr8 7:tr1
__global__ __launch_bounds__(256) void trace_kernel(const unsigned short* __restrict__ slab,
                                                    float* __restrict__ traces) {
    int m = blockIdx.x, t = threadIdx.x;
    int r  = blockIdx.y * 32 + (t >> 3);   // row
    int cs = (t & 7) * 32;                 // col segment (32 elems)
    const unsigned short* E = slab + (size_t)m * MSZ;
    const unsigned short* G = E + (size_t)11 * MSZ;
    const unsigned short* H = E + (size_t)22 * MSZ;
    const unsigned short* K = E + (size_t)33 * MSZ;

    float a0 = 0, a1 = 0, a2 = 0, a3 = 0, a4 = 0, a5 = 0, a6 = 0;
    float t1 = (r >= cs && r < cs + 32) ? bf2f(E[(size_t)r * 257]) : 0.f;
    size_t rb = (size_t)r * N_COLS + cs;
    #pragma unroll
    for (int cg = 0; cg < 32; cg += 8) {
        float e[8], g[8], h[8], k[8];
        unpack8(E + rb + cg, e);
        unpack8(G + rb + cg, g);
        unpack8(H + rb + cg, h);
        unpack8(K + rb + cg, k);
        #pragma unroll
        for (int j = 0; j < 8; ++j) {
            a0 = fmaf(e[j], e[j], a0);   // tr2
            a1 = fmaf(e[j], g[j], a1);   // tr3
            a2 = fmaf(g[j], g[j], a2);   // tr4
            a3 = fmaf(g[j], h[j], a3);   // tr5
            a4 = fmaf(h[j], h[j], a4);   // tr6
            a5 = fmaf(h[j], k[j], a5);   // tr7
            a6 = fmaf(k[j], k[j], a6);   // tr8
        }
    }
    float vals[8] = {a0, a1, a2, a3, a4, a5, a6, t1};
    #pragma unroll
    for (int v = 0; v < 8; ++v) {
        float x = vals[v];
        #pragma unroll
        for (int d = 32; d > 0; d >>= 1) x += __shfl_down(x, d, 64);
        if ((t & 63) == 0) atomicAdd(&traces[m * 16 + v], x);
    }
}

// ---------------- finalize (degree-8 series) ----------------
__global__ void finalize_kernel(const float* __restrict__ traces,
                                const float* __restrict__ cvals,
                                const int* __restrict__ meta,
                                float* __restrict__ out) {
    if (threadIdx.x == 0 && blockIdx.x == 0) {
        float logdet[11];
        for (int m = 0; m < 11; ++m) {
            const float* tr = traces + m * 16;
            logdet[m] = 256.f * __logf(cvals[m])
                      + tr[7]
                      - tr[0] / 2.f + tr[1] / 3.f - tr[2] / 4.f + tr[3] / 5.f
                      - tr[4] / 6.f + tr[5] / 7.f - tr[6] / 8.f;
        }
        float discrimn = 0.5f * logdet[NCLASS];       // GAM1 == 1 => empi == theo
        float compress = 0.f;
        for (int k = 0; k < NCLASS; ++k) {
            float trp = (float)meta[32 + k] + 1e-8f;
            compress += logdet[k] * trp;
        }
        compress = compress / (float)N_ROWS * 0.5f;
        out[0] = -discrimn + compress;                // GAM2 == 1
        out[1] = discrimn;
        out[2] = compress;
        out[3] = discrimn;
        out[4] = compress;
    }
}

extern "C" void kernel_launch(void* const* d_in, const int* in_sizes, int n_in,
                              void* d_out, int out_size, void* d_ws, size_t ws_size,
                              hipStream_t stream) {
    const float* X = (const float*)d_in[0];
    const int*   Y = (const int*)d_in[1];
    float* out = (float*)d_out;

    char* ws = (char*)d_ws;
    const size_t o_cov   = 0;                        // 10*256*256*4 = 2,621,440
    const size_t o_small = 2621440;                  // cvals (16 f) + traces (176 f); adjacent to cov -> one memset
    const size_t o_meta  = o_small + 1024;           // 64 ints
    const size_t o_blkc  = o_meta + 256;             // 2560 ints
    const size_t o_blkb  = o_blkc + 10240;           // 2560 ints
    const size_t o_order = o_blkb + 10240;           // 65536 ints
    const size_t o_xst   = o_order + 262144;         // 256*XP*2 = 33,882,112

    float*          cov      = (float*)(ws + o_cov);
    float*          cvals    = (float*)(ws + o_small);
    float*          traces   = (float*)(ws + o_small + 64);
    int*            meta     = (int*)(ws + o_meta);
    int*            blk_cnt  = (int*)(ws + o_blkc);
    int*            blk_base = (int*)(ws + o_blkb);
    int*            order    = (int*)(ws + o_order);
    unsigned short* Xst      = (unsigned short*)(ws + o_xst);
    unsigned short* slab     = Xst;                  // E/G/H/K overlay Xst after cov

    hipMemsetAsync(ws, 0, o_small + 1024, stream);   // cov + cvals + traces in one fill
    hipLaunchKernelGGL(blkhist_kernel, dim3(256), dim3(256), 0, stream, Y, blk_cnt);
    hipLaunchKernelGGL(scan_kernel, dim3(1), dim3(1024), 0, stream, blk_cnt, meta, blk_base);
    hipLaunchKernelGGL(order_kernel, dim3(256), dim3(256), 0, stream, Y, blk_base, order);
    hipLaunchKernelGGL(gather_kernel, dim3(XP / 64), dim3(256), 0, stream, X, order, meta, Xst);
    hipLaunchKernelGGL(cov_mfma, dim3(3, NCLASS, SPL), dim3(256), 0, stream, Xst, meta, cov);
    hipLaunchKernelGGL(prep_kernel, dim3(11, 32), dim3(256), 0, stream, cov, meta, cvals, slab);
    // S1: G = E*E
    hipLaunchKernelGGL(mm_stage, dim3(4, 11, 1), dim3(256), 0, stream, slab, 0, 0, 1, 0, 0, 1);
    // S2: H = E*G ; K = G*G
    hipLaunchKernelGGL(mm_stage, dim3(4, 11, 2), dim3(256), 0, stream, slab, 0, 1, 2, 1, 1, 3);
    hipLaunchKernelGGL(trace_kernel, dim3(11, 8), dim3(256), 0, stream, slab, traces);
    hipLaunchKernelGGL(finalize_kernel, dim3(1), dim3(64), 0, stream, traces, cvals, meta, out);
}

// Round 10
// 176.669 us; speedup vs baseline: 1.4494x; 1.0857x over previous
//
#include <hip/hip_runtime.h>

#define N_ROWS 65536
#define N_COLS 256
#define NCLASS 10
#define XP 66176            // Xst col pitch: 65536 + 10*64 pad
#define SPL 16              // K-splits per (class,tile)
#define MSZ 65536           // 256*256 elements per matrix

typedef __attribute__((ext_vector_type(8))) short bf16x8;
typedef __attribute__((ext_vector_type(4))) float f32x4;

// meta layout (ints): [0..10] off_pad, [16..26] offsets (unpadded), [32..41] counts
// slab layout (bf16): s*11*MSZ + m*MSZ for s in {0:E, 1:G=E^2, 2:H=E^3, 3:K=E^4}

static __device__ __forceinline__ unsigned short f2bf(float f) {
    unsigned int u = __float_as_uint(f);
    unsigned int r = (u + 0x7FFFu + ((u >> 16) & 1u)) >> 16;   // RTN-even
    return (unsigned short)r;
}
static __device__ __forceinline__ float bf2f(unsigned short s) {
    return __uint_as_float(((unsigned int)s) << 16);
}
static __device__ __forceinline__ void unpack8(const unsigned short* p, float* f) {
    uint4 u = *(const uint4*)p;
    f[0] = __uint_as_float(u.x << 16); f[1] = __uint_as_float(u.x & 0xffff0000u);
    f[2] = __uint_as_float(u.y << 16); f[3] = __uint_as_float(u.y & 0xffff0000u);
    f[4] = __uint_as_float(u.z << 16); f[5] = __uint_as_float(u.z & 0xffff0000u);
    f[6] = __uint_as_float(u.w << 16); f[7] = __uint_as_float(u.w & 0xffff0000u);
}
static __device__ __forceinline__ float scal_of(int b, const int* meta) {
    if (b < NCLASS) return (float)N_COLS / (((float)meta[32 + b] + 1e-8f) * 0.01f);
    return (float)N_COLS / ((float)N_ROWS * 0.01f);
}

// ---------------- Phase A: per-block class histogram (256 blocks) ----------------
__global__ __launch_bounds__(256) void blkhist_kernel(const int* __restrict__ Y,
                                                      int* __restrict__ blk_cnt) {
    __shared__ int h[NCLASS];
    int b = blockIdx.x, t = threadIdx.x;
    if (t < NCLASS) h[t] = 0;
    __syncthreads();
    atomicAdd(&h[Y[b * 256 + t]], 1);
    __syncthreads();
    if (t < NCLASS) blk_cnt[b * NCLASS + t] = h[t];
}

// ---------------- Phase B: scan (wave-per-class shuffle scans, 1 block) ----------------
__global__ __launch_bounds__(1024) void scan_kernel(const int* __restrict__ blk_cnt,
                                                    int* __restrict__ meta,
                                                    int* __restrict__ blk_base) {
    int t = threadIdx.x;
    int w = t >> 6, l = t & 63;
    __shared__ int tots[16];
    __shared__ int soff_s[16];
    int s0 = 0, s1 = 0, s2 = 0, s3 = 0;
    if (w < NCLASS) {
        s0 = blk_cnt[(l      ) * NCLASS + w];
        s1 = blk_cnt[(l +  64) * NCLASS + w];
        s2 = blk_cnt[(l + 128) * NCLASS + w];
        s3 = blk_cnt[(l + 192) * NCLASS + w];
    }
    int x0 = s0, x1 = s1, x2 = s2, x3 = s3;
    for (int d = 1; d < 64; d <<= 1) {
        int y0 = __shfl_up(x0, d, 64), y1 = __shfl_up(x1, d, 64);
        int y2 = __shfl_up(x2, d, 64), y3 = __shfl_up(x3, d, 64);
        if (l >= d) { x0 += y0; x1 += y1; x2 += y2; x3 += y3; }
    }
    int T0 = __shfl(x0, 63, 64), T1 = __shfl(x1, 63, 64);
    int T2 = __shfl(x2, 63, 64), T3 = __shfl(x3, 63, 64);
    if (w < NCLASS && l == 63) tots[w] = T0 + T1 + T2 + T3;
    __syncthreads();
    if (t == 0) {
        int off = 0, offp = 0;
        for (int c = 0; c < NCLASS; ++c) {
            soff_s[c] = off;
            meta[16 + c] = off;
            meta[c] = offp;
            meta[32 + c] = tots[c];
            off += tots[c];
            offp += (tots[c] + 63) & ~63;
        }
        meta[16 + NCLASS] = off;
        meta[NCLASS] = offp;
    }
    __syncthreads();
    if (w < NCLASS) {
        int base = soff_s[w];
        blk_base[(l      ) * NCLASS + w] = base + x0 - s0;
        blk_base[(l +  64) * NCLASS + w] = base + T0 + x1 - s1;
        blk_base[(l + 128) * NCLASS + w] = base + T0 + T1 + x2 - s2;
        blk_base[(l + 192) * NCLASS + w] = base + T0 + T1 + T2 + x3 - s3;
    }
}

// ---------------- Phase C: build sorted order (256 blocks) ----------------
__global__ __launch_bounds__(256) void order_kernel(const int* __restrict__ Y,
                                                    const int* __restrict__ blk_base,
                                                    int* __restrict__ order) {
    __shared__ int lcur[NCLASS];
    int b = blockIdx.x, t = threadIdx.x;
    if (t < NCLASS) lcur[t] = 0;
    __syncthreads();
    int i = b * 256 + t;
    int y = Y[i];
    int pos = blk_base[b * NCLASS + y] + atomicAdd(&lcur[y], 1);
    order[pos] = i;
}

// ---------------- gather + fp32->bf16 + transpose (rotation-swizzled LDS) ----------------
__global__ __launch_bounds__(256) void gather_kernel(const float* __restrict__ X,
                                                     const int* __restrict__ order,
                                                     const int* __restrict__ meta,
                                                     unsigned short* __restrict__ Xst) {
    __shared__ unsigned int sT32[256 * 32];   // 32 KB
    int p0 = blockIdx.x * 64;
    if (p0 >= meta[NCLASS]) return;
    int cls = 0;
    while (p0 >= meta[cls + 1]) ++cls;       // 64-tiles never straddle classes
    int lp0 = p0 - meta[cls];
    int cnt = meta[32 + cls];
    int obase = meta[16 + cls];

    int t = threadIdx.x;
    int w = t >> 6, l = t & 63;

    #pragma unroll
    for (int rp = 0; rp < 8; ++rp) {
        int p2 = w * 8 + rp;                  // 0..31 (pos pair index)
        int lpa = lp0 + p2 * 2;
        int lpb = lpa + 1;
        int ra = (lpa < cnt) ? order[obase + lpa] : -1;   // wave-uniform
        int rb = (lpb < cnt) ? order[obase + lpb] : -1;
        float4 va = make_float4(0.f, 0.f, 0.f, 0.f);
        float4 vb = make_float4(0.f, 0.f, 0.f, 0.f);
        if (ra >= 0) va = *(const float4*)(X + (size_t)ra * N_COLS + l * 4);
        if (rb >= 0) vb = *(const float4*)(X + (size_t)rb * N_COLS + l * 4);
        unsigned int d0 = (unsigned)f2bf(va.x) | ((unsigned)f2bf(vb.x) << 16);
        unsigned int d1 = (unsigned)f2bf(va.y) | ((unsigned)f2bf(vb.y) << 16);
        unsigned int d2 = (unsigned)f2bf(va.z) | ((unsigned)f2bf(vb.z) << 16);
        unsigned int d3 = (unsigned)f2bf(va.w) | ((unsigned)f2bf(vb.w) << 16);
        int c0 = l * 4;
        sT32[(c0 + 0) * 32 + ((p2 + l) & 31)] = d0;   // (c0+j)>>2 == l
        sT32[(c0 + 1) * 32 + ((p2 + l) & 31)] = d1;
        sT32[(c0 + 2) * 32 + ((p2 + l) & 31)] = d2;
        sT32[(c0 + 3) * 32 + ((p2 + l) & 31)] = d3;
    }
    __syncthreads();

    int cb = t >> 3, pc = t & 7;
    #pragma unroll
    for (int j = 0; j < 8; ++j) {
        int col = cb + j * 32;
        int rot = col >> 2;
        const unsigned int* base = &sT32[col * 32];
        uint4 o;
        o.x = base[(pc * 4 + 0 + rot) & 31];
        o.y = base[(pc * 4 + 1 + rot) & 31];
        o.z = base[(pc * 4 + 2 + rot) & 31];
        o.w = base[(pc * 4 + 3 + rot) & 31];
        *(uint4*)(Xst + (size_t)col * XP + p0 + pc * 8) = o;
    }
}

// ---------------- cov via bf16 MFMA syrk -> per-split partial tiles (no atomics) ----------------
// part[s][cls][tile][128*128], tile 0:(0,0) 1:(0,1) 2:(1,1). Every block writes its
// full tile (zero if its split got no chunks) so no zero-init is needed.
__global__ __launch_bounds__(256) void cov_mfma(const unsigned short* __restrict__ Xst,
                                                const int* __restrict__ meta,
                                                float* __restrict__ part) {
    __shared__ unsigned short sA[128][72];
    __shared__ unsigned short sB[128][72];
    int cls = blockIdx.y;
    int tile = blockIdx.x;
    int ti = (tile == 2) ? 1 : 0;
    int tj = (tile == 0) ? 0 : 1;
    int kb = meta[cls];
    int len = meta[cls + 1] - kb;
    int nch = len >> 6;
    int s = blockIdx.z;
    int ch0 = (nch * s) / SPL, ch1 = (nch * (s + 1)) / SPL;

    int t = threadIdx.x;
    int lane = t & 63, wave = t >> 6;
    int wro = (wave >> 1) * 64, wco = (wave & 1) * 64;

    f32x4 acc[4][4] = {};

    int sr = t >> 1;
    int sq = (t & 1) * 32;

    for (int ch = ch0; ch < ch1; ++ch) {
        int k0 = kb + ch * 64;
        const uint4* ga = (const uint4*)(Xst + (size_t)(ti * 128 + sr) * XP + k0 + sq);
        const uint4* gb = (const uint4*)(Xst + (size_t)(tj * 128 + sr) * XP + k0 + sq);
        uint4 a0 = ga[0], a1 = ga[1], a2 = ga[2], a3 = ga[3];
        uint4 b0 = gb[0], b1 = gb[1], b2 = gb[2], b3 = gb[3];
        __syncthreads();
        *(uint4*)&sA[sr][sq]      = a0;
        *(uint4*)&sA[sr][sq + 8]  = a1;
        *(uint4*)&sA[sr][sq + 16] = a2;
        *(uint4*)&sA[sr][sq + 24] = a3;
        *(uint4*)&sB[sr][sq]      = b0;
        *(uint4*)&sB[sr][sq + 8]  = b1;
        *(uint4*)&sB[sr][sq + 16] = b2;
        *(uint4*)&sB[sr][sq + 24] = b3;
        __syncthreads();
        #pragma unroll
        for (int ks = 0; ks < 64; ks += 32) {
            bf16x8 af[4], bfr[4];
            #pragma unroll
            for (int r = 0; r < 4; ++r)
                af[r] = *(const bf16x8*)&sA[wro + r * 16 + (lane & 15)][ks + (lane >> 4) * 8];
            #pragma unroll
            for (int c2 = 0; c2 < 4; ++c2)
                bfr[c2] = *(const bf16x8*)&sB[wco + c2 * 16 + (lane & 15)][ks + (lane >> 4) * 8];
            #pragma unroll
            for (int r = 0; r < 4; ++r) {
                #pragma unroll
                for (int c2 = 0; c2 < 4; ++c2)
                    acc[r][c2] = __builtin_amdgcn_mfma_f32_16x16x32_bf16(af[r], bfr[c2], acc[r][c2], 0, 0, 0);
            }
        }
    }

    float* po = part + (((size_t)s * NCLASS + cls) * 3 + tile) * 16384;
    int prl = wro + ((lane >> 4) << 2);
    int pcl = wco + (lane & 15);
    #pragma unroll
    for (int r = 0; r < 4; ++r) {
        #pragma unroll
        for (int c2 = 0; c2 < 4; ++c2) {
            #pragma unroll
            for (int v = 0; v < 4; ++v)
                po[(size_t)(prl + r * 16 + v) * 128 + pcl + c2 * 16] = acc[r][c2][v];
        }
    }
}

// ---------------- merge: sum SPL partials -> cov (upper-block layout) ----------------
// grid (30, 8): block = (cls*3+tile, 16-row chunk); thread sums 16 splits of 8 elems.
__global__ __launch_bounds__(256) void merge_kernel(const float* __restrict__ part,
                                                    float* __restrict__ cov) {
    int u = blockIdx.x;
    int cls = u / 3, tile = u % 3;
    int t = threadIdx.x;
    int lr = blockIdx.y * 16 + (t >> 4);   // local row 0..127
    int lc = (t & 15) * 8;                 // local col
    size_t off = (size_t)lr * 128 + lc;
    float4 s0 = make_float4(0.f, 0.f, 0.f, 0.f);
    float4 s1 = make_float4(0.f, 0.f, 0.f, 0.f);
    for (int s = 0; s < SPL; ++s) {
        const float* pb = part + (((size_t)s * NCLASS + cls) * 3 + tile) * 16384;
        float4 a = *(const float4*)(pb + off);
        float4 b = *(const float4*)(pb + off + 4);
        s0.x += a.x; s0.y += a.y; s0.z += a.z; s0.w += a.w;
        s1.x += b.x; s1.y += b.y; s1.z += b.z; s1.w += b.w;
    }
    int gr = (tile == 2 ? 128 : 0) + lr;
    int gc = (tile == 0 ? 0 : 128) + lc;
    float* cb = cov + (size_t)cls * MSZ + (size_t)gr * N_COLS + gc;
    *(float4*)cb = s0;
    *(float4*)(cb + 4) = s1;
}

// ---------------- prep: inline cvals + E_b = M_b/c_b - I (bf16); grid (11, 32) ----------------
__global__ __launch_bounds__(256) void prep_kernel(const float* __restrict__ cov,
                                                   const int* __restrict__ meta,
                                                   float* __restrict__ cvals,
                                                   unsigned short* __restrict__ slab) {
    int b = blockIdx.x;   // matrix 0..10
    int t = threadIdx.x;
    float scal = scal_of(b, meta);

    float dsum;
    if (b < NCLASS) dsum = cov[(size_t)b * MSZ + t * 257];
    else {
        dsum = 0.f;
        #pragma unroll
        for (int cl = 0; cl < NCLASS; ++cl) dsum += cov[(size_t)cl * MSZ + t * 257];
    }
    __shared__ float red[256];
    red[t] = dsum;
    __syncthreads();
    for (int s = 128; s > 0; s >>= 1) {
        if (t < s) red[t] += red[t + s];
        __syncthreads();
    }
    float c = 1.f + scal * red[0] / 256.f;
    if (blockIdx.y == 0 && t == 0) cvals[b] = c;
    float es = scal / c;
    float dadd = 1.f / c - 1.f;

    int i  = blockIdx.y * 8 + (t >> 5);   // row
    int cg = (t & 31) * 8;                // col group (8 elems)
    bool mb = (i >> 7) > (cg >> 7);       // cov stores upper 128-blocks; mirror (1,0)
    float v[8];
    if (!mb) {
        size_t off = (size_t)i * N_COLS + cg;
        if (b < NCLASS) {
            float4 a = *(const float4*)(cov + (size_t)b * MSZ + off);
            float4 bq = *(const float4*)(cov + (size_t)b * MSZ + off + 4);
            v[0] = a.x; v[1] = a.y; v[2] = a.z; v[3] = a.w;
            v[4] = bq.x; v[5] = bq.y; v[6] = bq.z; v[7] = bq.w;
        } else {
            #pragma unroll
            for (int jj = 0; jj < 8; ++jj) v[jj] = 0.f;
            #pragma unroll
            for (int cl = 0; cl < NCLASS; ++cl) {
                float4 a = *(const float4*)(cov + (size_t)cl * MSZ + off);
                float4 bq = *(const float4*)(cov + (size_t)cl * MSZ + off + 4);
                v[0] += a.x; v[1] += a.y; v[2] += a.z; v[3] += a.w;
                v[4] += bq.x; v[5] += bq.y; v[6] += bq.z; v[7] += bq.w;
            }
        }
    } else {
        #pragma unroll
        for (int jj = 0; jj < 8; ++jj) {
            size_t off = (size_t)(cg + jj) * N_COLS + i;
            float s;
            if (b < NCLASS) s = cov[(size_t)b * MSZ + off];
            else {
                s = 0.f;
                #pragma unroll
                for (int cl = 0; cl < NCLASS; ++cl) s += cov[(size_t)cl * MSZ + off];
            }
            v[jj] = s;
        }
    }
    unsigned short o[8];
    #pragma unroll
    for (int jj = 0; jj < 8; ++jj)
        o[jj] = f2bf(es * v[jj] + ((cg + jj) == i ? dadd : 0.f));
    uint4 pk;
    pk.x = (unsigned)o[0] | ((unsigned)o[1] << 16);
    pk.y = (unsigned)o[2] | ((unsigned)o[3] << 16);
    pk.z = (unsigned)o[4] | ((unsigned)o[5] << 16);
    pk.w = (unsigned)o[6] | ((unsigned)o[7] << 16);
    *(uint4*)&slab[(size_t)b * MSZ + (size_t)i * N_COLS + cg] = pk;
}

// ---------------- mm_stage: D = A*B for symmetric bf16 256x256 (MFMA) ----------------
__global__ __launch_bounds__(256) void mm_stage(unsigned short* __restrict__ slab,
                                                int ai0, int bi0, int di0,
                                                int ai1, int bi1, int di1) {
    int z = blockIdx.z;
    int ai = z ? ai1 : ai0, bi = z ? bi1 : bi0, di = z ? di1 : di0;
    int m = blockIdx.y;
    int tile = blockIdx.x;
    int ti = tile >> 1, tj = tile & 1;
    const unsigned short* A = slab + ((size_t)ai * 11 + m) * MSZ;
    const unsigned short* B = slab + ((size_t)bi * 11 + m) * MSZ;
    unsigned short* D = slab + ((size_t)di * 11 + m) * MSZ;

    __shared__ unsigned short sA[128][72];
    __shared__ unsigned short sB[128][72];
    int t = threadIdx.x;
    int lane = t & 63, wave = t >> 6;
    int wro = (wave >> 1) * 64, wco = (wave & 1) * 64;

    f32x4 acc[4][4] = {};
    int sr = t >> 1;
    int sq = (t & 1) * 32;

    for (int ch = 0; ch < 4; ++ch) {
        int k0 = ch * 64;
        const uint4* ga = (const uint4*)(A + (size_t)(ti * 128 + sr) * N_COLS + k0 + sq);
        const uint4* gb = (const uint4*)(B + (size_t)(tj * 128 + sr) * N_COLS + k0 + sq);
        uint4 a0 = ga[0], a1 = ga[1], a2 = ga[2], a3 = ga[3];
        uint4 b0 = gb[0], b1 = gb[1], b2 = gb[2], b3 = gb[3];
        __syncthreads();
        *(uint4*)&sA[sr][sq]      = a0;
        *(uint4*)&sA[sr][sq + 8]  = a1;
        *(uint4*)&sA[sr][sq + 16] = a2;
        *(uint4*)&sA[sr][sq + 24] = a3;
        *(uint4*)&sB[sr][sq]      = b0;
        *(uint4*)&sB[sr][sq + 8]  = b1;
        *(uint4*)&sB[sr][sq + 16] = b2;
        *(uint4*)&sB[sr][sq + 24] = b3;
        __syncthreads();
        #pragma unroll
        for (int ks = 0; ks < 64; ks += 32) {
            bf16x8 af[4], bfr[4];
            #pragma unroll
            for (int r = 0; r < 4; ++r)
                af[r] = *(const bf16x8*)&sA[wro + r * 16 + (lane & 15)][ks + (lane >> 4) * 8];
            #pragma unroll
            for (int c2 = 0; c2 < 4; ++c2)
                bfr[c2] = *(const bf16x8*)&sB[wco + c2 * 16 + (lane & 15)][ks + (lane >> 4) * 8];
            #pragma unroll
            for (int r = 0; r < 4; ++r) {
                #pragma unroll
                for (int c2 = 0; c2 < 4; ++c2)
                    acc[r][c2] = __builtin_amdgcn_mfma_f32_16x16x32_bf16(af[r], bfr[c2], acc[r][c2], 0, 0, 0);
            }
        }
    }

    int prow = ti * 128 + wro + ((lane >> 4) << 2);
    int pcol = tj * 128 + wco + (lane & 15);
    #pragma unroll
    for (int r = 0; r < 4; ++r) {
        #pragma unroll
        for (int c2 = 0; c2 < 4; ++c2) {
            #pragma unroll
            for (int v = 0; v < 4; ++v)
                D[(size_t)(prow + r * 16 + v) * N_COLS + pcol + c2 * 16] = f2bf(acc[r][c2][v]);
        }
    }
}

// ---------------- trace: pairings of E,G,H,K -> tr(E^k), k=1..8; grid (11, 8) ----------------
// traces[m*16 + v]: v=0:tr2 1:tr3 2:tr4 3:tr5 4:tr6 5:tr7 6:tr8 7:tr1
__global__ __launch_bounds__(256) void trace_kernel(const unsigned short* __restrict__ slab,
                                                    float* __restrict__ traces) {
    int m = blockIdx.x, t = threadIdx.x;
    int r  = blockIdx.y * 32 + (t >> 3);   // row
    int cs = (t & 7) * 32;                 // col segment (32 elems)
    const unsigned short* E = slab + (size_t)m * MSZ;
    const unsigned short* G = E + (size_t)11 * MSZ;
    const unsigned short* H = E + (size_t)22 * MSZ;
    const unsigned short* K = E + (size_t)33 * MSZ;

    float a0 = 0, a1 = 0, a2 = 0, a3 = 0, a4 = 0, a5 = 0, a6 = 0;
    float t1 = (r >= cs && r < cs + 32) ? bf2f(E[(size_t)r * 257]) : 0.f;
    size_t rb = (size_t)r * N_COLS + cs;
    #pragma unroll
    for (int cg = 0; cg < 32; cg += 8) {
        float e[8], g[8], h[8], k[8];
        unpack8(E + rb + cg, e);
        unpack8(G + rb + cg, g);
        unpack8(H + rb + cg, h);
        unpack8(K + rb + cg, k);
        #pragma unroll
        for (int j = 0; j < 8; ++j) {
            a0 = fmaf(e[j], e[j], a0);   // tr2
            a1 = fmaf(e[j], g[j], a1);   // tr3
            a2 = fmaf(g[j], g[j], a2);   // tr4
            a3 = fmaf(g[j], h[j], a3);   // tr5
            a4 = fmaf(h[j], h[j], a4);   // tr6
            a5 = fmaf(h[j], k[j], a5);   // tr7
            a6 = fmaf(k[j], k[j], a6);   // tr8
        }
    }
    float vals[8] = {a0, a1, a2, a3, a4, a5, a6, t1};
    #pragma unroll
    for (int v = 0; v < 8; ++v) {
        float x = vals[v];
        #pragma unroll
        for (int d = 32; d > 0; d >>= 1) x += __shfl_down(x, d, 64);
        if ((t & 63) == 0) atomicAdd(&traces[m * 16 + v], x);
    }
}

// ---------------- finalize (degree-8 series) ----------------
__global__ void finalize_kernel(const float* __restrict__ traces,
                                const float* __restrict__ cvals,
                                const int* __restrict__ meta,
                                float* __restrict__ out) {
    if (threadIdx.x == 0 && blockIdx.x == 0) {
        float logdet[11];
        for (int m = 0; m < 11; ++m) {
            const float* tr = traces + m * 16;
            logdet[m] = 256.f * __logf(cvals[m])
                      + tr[7]
                      - tr[0] / 2.f + tr[1] / 3.f - tr[2] / 4.f + tr[3] / 5.f
                      - tr[4] / 6.f + tr[5] / 7.f - tr[6] / 8.f;
        }
        float discrimn = 0.5f * logdet[NCLASS];       // GAM1 == 1 => empi == theo
        float compress = 0.f;
        for (int k = 0; k < NCLASS; ++k) {
            float trp = (float)meta[32 + k] + 1e-8f;
            compress += logdet[k] * trp;
        }
        compress = compress / (float)N_ROWS * 0.5f;
        out[0] = -discrimn + compress;                // GAM2 == 1
        out[1] = discrimn;
        out[2] = compress;
        out[3] = discrimn;
        out[4] = compress;
    }
}

extern "C" void kernel_launch(void* const* d_in, const int* in_sizes, int n_in,
                              void* d_out, int out_size, void* d_ws, size_t ws_size,
                              hipStream_t stream) {
    const float* X = (const float*)d_in[0];
    const int*   Y = (const int*)d_in[1];
    float* out = (float*)d_out;

    char* ws = (char*)d_ws;
    const size_t o_cov   = 0;                        // 10*256*256*4 = 2,621,440 (written by merge)
    const size_t o_small = 2621440;                  // cvals (16 f) + traces (176 f)
    const size_t o_meta  = o_small + 1024;           // 64 ints
    const size_t o_blkc  = o_meta + 256;             // 2560 ints
    const size_t o_blkb  = o_blkc + 10240;           // 2560 ints
    const size_t o_order = o_blkb + 10240;           // 65536 ints
    const size_t o_part  = o_order + 262144;         // 16*10*3*16384*4 = 31,457,280
    const size_t o_xst   = o_part + 31457280;        // 256*XP*2 = 33,882,112

    float*          cov      = (float*)(ws + o_cov);
    float*          cvals    = (float*)(ws + o_small);
    float*          traces   = (float*)(ws + o_small + 64);
    int*            meta     = (int*)(ws + o_meta);
    int*            blk_cnt  = (int*)(ws + o_blkc);
    int*            blk_base = (int*)(ws + o_blkb);
    int*            order    = (int*)(ws + o_order);
    float*          part     = (float*)(ws + o_part);
    unsigned short* Xst      = (unsigned short*)(ws + o_xst);
    unsigned short* slab     = Xst;                  // E/G/H/K overlay Xst after cov

    hipMemsetAsync(ws + o_small, 0, 1024, stream);   // only cvals+traces need zeroing now
    hipLaunchKernelGGL(blkhist_kernel, dim3(256), dim3(256), 0, stream, Y, blk_cnt);
    hipLaunchKernelGGL(scan_kernel, dim3(1), dim3(1024), 0, stream, blk_cnt, meta, blk_base);
    hipLaunchKernelGGL(order_kernel, dim3(256), dim3(256), 0, stream, Y, blk_base, order);
    hipLaunchKernelGGL(gather_kernel, dim3(XP / 64), dim3(256), 0, stream, X, order, meta, Xst);
    hipLaunchKernelGGL(cov_mfma, dim3(3, NCLASS, SPL), dim3(256), 0, stream, Xst, meta, part);
    hipLaunchKernelGGL(merge_kernel, dim3(30, 8), dim3(256), 0, stream, part, cov);
    hipLaunchKernelGGL(prep_kernel, dim3(11, 32), dim3(256), 0, stream, cov, meta, cvals, slab);
    // S1: G = E*E
    hipLaunchKernelGGL(mm_stage, dim3(4, 11, 1), dim3(256), 0, stream, slab, 0, 0, 1, 0, 0, 1);
    // S2: H = E*G ; K = G*G
    hipLaunchKernelGGL(mm_stage, dim3(4, 11, 2), dim3(256), 0, stream, slab, 0, 1, 2, 1, 1, 3);
    hipLaunchKernelGGL(trace_kernel, dim3(11, 8), dim3(256), 0, stream, slab, traces);
    hipLaunchKernelGGL(finalize_kernel, dim3(1), dim3(64), 0, stream, traces, cvals, meta, out);
}